// Round 1
// baseline (117.679 us; speedup 1.0000x reference)
//
#include <hip/hip_runtime.h>

// Karplus-Strong waveguide, collapsed to a single fixed-point recurrence:
//   S_l[t] = 0.5*exc[t-nDown] + g_b*(c0*S_r[t-L] + c1*S_r[t-L-1] + c2*S_r[t-L-2])
//   S_r[t] = 0.5*exc[t-nUp]   + g_n*(d0*S_l[t-L] + d1*S_l[t-L-1])
//   out[t] = S_l[t] + S_r[t]
// where c = dispersion∘bridge_lp (3 taps), d = dispersion (2 taps).
// Chunk [m*L,(m+1)*L) depends only on samples < m*L  ->  400 phases x 240 lanes.

__global__ __launch_bounds__(256, 1)
void guitar_kernel(const int* __restrict__ lengthp,
                   const float* __restrict__ pluckp,
                   const float* __restrict__ exc,
                   const float* __restrict__ gnp,
                   const float* __restrict__ gbp,
                   const float* __restrict__ bbp,
                   const float* __restrict__ dap,
                   float* __restrict__ out, int T) {
    const int   L     = lengthp[0];        // 240
    const float pluck = pluckp[0];
    const float gn = gnp[0];               // nut reflection gain
    const float gb = gbp[0];               // bridge reflection gain
    const float bb = bbp[0];               // bridge one-zero lowpass coeff
    const float da = dap[0];               // dispersion FIR coeff

    const int nUp   = (int)rintf((float)L * pluck);  // round-half-even, matches jnp.round
    const int nDown = L - nUp;

    // composite filter taps: disp(lp(x))[s] = c0*x[s] + c1*x[s-1] + c2*x[s-2]
    const float c0 = da * (1.0f - bb);
    const float c1 = da * bb + (1.0f - da) * (1.0f - bb);
    const float c2 = (1.0f - da) * bb;
    const float d0 = da;
    const float d1 = 1.0f - da;

    __shared__ float sl[512];   // ring buffers: slot = t & 511; need 242-deep history
    __shared__ float sr[512];

    const int tid = threadIdx.x;
    for (int i = tid; i < 512; i += 256) { sl[i] = 0.0f; sr[i] = 0.0f; }
    __syncthreads();   // negative-index reads in phases 0/1 hit untouched (zero) slots

    const int nphase = (T + L - 1) / L;    // 400

    // prefetch phase-0 excitation
    float exd = 0.0f, exu = 0.0f;
    if (tid < L) {
        int id = tid - nDown; exd = (id >= 0) ? exc[id] : 0.0f;
        int iu = tid - nUp;   exu = (iu >= 0) ? exc[iu] : 0.0f;
    }

    for (int m = 0; m < nphase; ++m) {
        // prefetch next phase's excitation (latency hidden under this phase)
        float exd_n = 0.0f, exu_n = 0.0f;
        {
            int tn = (m + 1) * L + tid;
            if (tid < L && tn < T) {
                int id = tn - nDown; exd_n = (id >= 0) ? exc[id] : 0.0f;
                int iu = tn - nUp;   exu_n = (iu >= 0) ? exc[iu] : 0.0f;
            }
        }

        if (tid < L) {
            const int t  = m * L + tid;
            const int tm = t - L;
            // history reads (slots provably disjoint from this phase's writes mod 512)
            const float sr0 = sr[(tm    ) & 511];
            const float sr1 = sr[(tm - 1) & 511];
            const float sr2 = sr[(tm - 2) & 511];
            const float sl0 = sl[(tm    ) & 511];
            const float sl1 = sl[(tm - 1) & 511];

            const float Sl = 0.5f * exd + gb * (c0 * sr0 + c1 * sr1 + c2 * sr2);
            const float Sr = 0.5f * exu + gn * (d0 * sl0 + d1 * sl1);

            sl[t & 511] = Sl;
            sr[t & 511] = Sr;
            if (t < T) out[t] = Sl + Sr;
        }

        exd = exd_n; exu = exu_n;
        __syncthreads();   // one barrier per phase (in-phase R/W slot sets are disjoint)
    }
}

extern "C" void kernel_launch(void* const* d_in, const int* in_sizes, int n_in,
                              void* d_out, int out_size, void* d_ws, size_t ws_size,
                              hipStream_t stream) {
    const int*   length = (const int*)  d_in[0];
    const float* pluck  = (const float*)d_in[1];
    const float* exc    = (const float*)d_in[2];
    const float* gn     = (const float*)d_in[3];
    const float* gb     = (const float*)d_in[4];
    const float* bb     = (const float*)d_in[5];
    const float* da     = (const float*)d_in[6];
    float* out = (float*)d_out;

    guitar_kernel<<<1, 256, 0, stream>>>(length, pluck, exc, gn, gb, bb, da, out, out_size);
}

// Round 2
// 88.294 us; speedup vs baseline: 1.3328x; 1.3328x over previous
//
#include <hip/hip_runtime.h>

// Karplus-Strong waveguide, decoupled + lag-doubled.
//
// Base (validated round 1):
//   S_l[t] = 0.5*exd[t] + gb*(c ⊛ S_r)[t-L]
//   S_r[t] = 0.5*exu[t] + gn*(d ⊛ S_l)[t-L]
// Substituting each into the other decouples them:
//   S[t] = D[t] + g*(e ⊛ S)[t-2L],   e = c⊛d (4 taps), g = gb*gn
// with data-parallel driving terms D_l, D_r (short FIRs of the excitation).
// Expanding the geometric series to n=3:
//   D2 = D + g*e⊛D(2L) + g^2*(e⊛e)⊛D(4L) + g^3*(e⊛e⊛e)⊛D(6L)
//   S[t] = D2[t] + g^4 * (e^{⊛4} ⊛ S)[t-8L]        (13-tap filter f, lag P=8L)
// -> prep kernel (grid-parallel) computes D2_l, D2_r; sequential kernel runs
//    only T/P = 50 phases of 8L=1920 samples, with raw s_barrier (lgkm-only
//    drain) so global prefetch/stores pipeline across phases.

#define SEQ_BLK 512
#define BUFSZ   1040   // float4 per ring (supports L<=256: needs 4L+9)

static __device__ __forceinline__ float exg(const float* __restrict__ e, int i) {
    return (i >= 0) ? e[i] : 0.0f;
}

struct Taps {
    int L, nUp, nDown, P0, P;
    float gb, gn;
    float c0, c1, c2, d0, d1;
    float w1[4], w2[7], w3[10];  // g*e, g^2*(e*e), g^3*(e*e*e)
    float f[13];                 // e^{*4}
    float g4;
};

static __device__ __forceinline__ Taps mk(const int* Lp, const float* pk,
                                          const float* gnp, const float* gbp,
                                          const float* bbp, const float* dap) {
    Taps tp;
    tp.L = Lp[0];
    const float pluck = pk[0];
    tp.gn = gnp[0]; tp.gb = gbp[0];
    const float bb = bbp[0], da = dap[0];
    tp.nUp = (int)rintf((float)tp.L * pluck);   // round-half-even == jnp.round
    tp.nDown = tp.L - tp.nUp;
    tp.P0 = 2 * tp.L;
    tp.P  = 8 * tp.L;
    tp.c0 = da * (1.f - bb);
    tp.c1 = da * bb + (1.f - da) * (1.f - bb);
    tp.c2 = (1.f - da) * bb;
    tp.d0 = da; tp.d1 = 1.f - da;
    const float e[4] = { tp.c0*tp.d0, tp.c0*tp.d1 + tp.c1*tp.d0,
                         tp.c1*tp.d1 + tp.c2*tp.d0, tp.c2*tp.d1 };
    float ee[7] = {0,0,0,0,0,0,0};
#pragma unroll
    for (int i = 0; i < 4; ++i)
#pragma unroll
        for (int j = 0; j < 4; ++j) ee[i+j] += e[i]*e[j];
    float e3[10] = {0,0,0,0,0,0,0,0,0,0};
#pragma unroll
    for (int i = 0; i < 7; ++i)
#pragma unroll
        for (int j = 0; j < 4; ++j) e3[i+j] += ee[i]*e[j];
    float f4t[13] = {0,0,0,0,0,0,0,0,0,0,0,0,0};
#pragma unroll
    for (int i = 0; i < 7; ++i)
#pragma unroll
        for (int j = 0; j < 7; ++j) f4t[i+j] += ee[i]*ee[j];
    const float g = tp.gb * tp.gn, g2 = g*g, g3 = g2*g;
#pragma unroll
    for (int k = 0; k < 4;  ++k) tp.w1[k] = g  * e[k];
#pragma unroll
    for (int k = 0; k < 7;  ++k) tp.w2[k] = g2 * ee[k];
#pragma unroll
    for (int k = 0; k < 10; ++k) tp.w3[k] = g3 * e3[k];
#pragma unroll
    for (int k = 0; k < 13; ++k) tp.f[k] = f4t[k];
    tp.g4 = g2 * g2;
    return tp;
}

// ---------------- prep: D2_l, D2_r (fully parallel over t) ----------------
__global__ void prep_kernel(const int* Lp, const float* pk,
                            const float* __restrict__ exc,
                            const float* gnp, const float* gbp,
                            const float* bbp, const float* dap,
                            float* __restrict__ D2l, float* __restrict__ D2r, int T) {
    const int t = blockIdx.x * blockDim.x + threadIdx.x;
    if (t >= T) return;
    const Taps tp = mk(Lp, pk, gnp, gbp, bbp, dap);

    auto Dl = [&](int s) -> float {
        if (s < 0) return 0.f;
        float v = 0.5f * exg(exc, s - tp.nDown);
        v += (0.5f * tp.gb) * (tp.c0 * exg(exc, s - tp.L     - tp.nUp)
                             + tp.c1 * exg(exc, s - tp.L - 1 - tp.nUp)
                             + tp.c2 * exg(exc, s - tp.L - 2 - tp.nUp));
        return v;
    };
    auto Dr = [&](int s) -> float {
        if (s < 0) return 0.f;
        float v = 0.5f * exg(exc, s - tp.nUp);
        v += (0.5f * tp.gn) * (tp.d0 * exg(exc, s - tp.L     - tp.nDown)
                             + tp.d1 * exg(exc, s - tp.L - 1 - tp.nDown));
        return v;
    };

    float al = Dl(t), ar = Dr(t);
#pragma unroll
    for (int k = 0; k < 4;  ++k) { const int s = t -     tp.P0 - k; al += tp.w1[k]*Dl(s); ar += tp.w1[k]*Dr(s); }
#pragma unroll
    for (int k = 0; k < 7;  ++k) { const int s = t - 2 * tp.P0 - k; al += tp.w2[k]*Dl(s); ar += tp.w2[k]*Dr(s); }
#pragma unroll
    for (int k = 0; k < 10; ++k) { const int s = t - 3 * tp.P0 - k; al += tp.w3[k]*Dl(s); ar += tp.w3[k]*Dr(s); }
    D2l[t] = al; D2r[t] = ar;
}

// ---------------- sequential: 50 phases of P=8L samples ----------------
// LDS layout per array (floats): [Pre0(16) | R0(P) | Pre1(16) | R1(P)]
// chunk q lives in half q&1; Pre_h holds chunk-(q-2)'s last 16 samples so
// window reads [t-P-12, t-P+7] are linear (never wrap). Tail values are
// written one phase late (no same-phase read/write overlap anywhere).
__global__ __launch_bounds__(SEQ_BLK, 1)
void seq_kernel(const int* Lp, const float* pk,
                const float* gnp, const float* gbp, const float* bbp, const float* dap,
                const float* __restrict__ D2l, const float* __restrict__ D2r,
                float* __restrict__ out, int T) {
    __shared__ float4 lb[BUFSZ];
    __shared__ float4 rb[BUFSZ];

    const Taps tp = mk(Lp, pk, gnp, gbp, bbp, dap);
    const int L = tp.L, P = tp.P, P4 = P >> 2;
    const int tid = threadIdx.x;
    const bool isL = (tid < L);
    const bool isR = (tid >= 256) && (tid < 256 + L);
    const bool act = isL || isR;
    const int lane = isL ? tid : (tid - 256);
    const float* __restrict__ D2 = isL ? D2l : D2r;
    float4* buf = isL ? lb : rb;

    for (int i = tid; i < BUFSZ; i += SEQ_BLK) {
        lb[i] = float4{0.f,0.f,0.f,0.f};
        rb[i] = float4{0.f,0.f,0.f,0.f};
    }
    __syncthreads();

    const int nphase  = (T + P - 1) / P;
    const int hstride = P4 + 4;

    // chunk-0 driving terms
    float4 d2a = {0,0,0,0}, d2b = {0,0,0,0};
    if (act) {
        const int t0 = lane * 8;
        if (t0 + 8 <= T) { d2a = *(const float4*)(D2 + t0); d2b = *(const float4*)(D2 + t0 + 4); }
        else {
            float tmp[8];
#pragma unroll
            for (int s = 0; s < 8; ++s) tmp[s] = (t0 + s < T) ? D2[t0 + s] : 0.f;
            d2a = float4{tmp[0],tmp[1],tmp[2],tmp[3]};
            d2b = float4{tmp[4],tmp[5],tmp[6],tmp[7]};
        }
    }

    float4 pS0 = {0,0,0,0}, pS1 = {0,0,0,0};   // previous chunk's 8 samples

    for (int q = 0; q <= nphase; ++q) {
        const int h   = q & 1;
        const int b4w = 4 + h * hstride;         // write base (f4) of half h
        const int b4r = 4 + (1 - h) * hstride;   // read  base (f4) of half 1-h

        // (1) prefetch next chunk's D2 (stays in flight across raw barrier)
        float4 nd2a = {0,0,0,0}, nd2b = {0,0,0,0};
        if (act && (q + 1) < nphase) {
            const int t1 = (q + 1) * P + lane * 8;
            if (t1 + 8 <= T) { nd2a = *(const float4*)(D2 + t1); nd2b = *(const float4*)(D2 + t1 + 4); }
            else {
                float tmp[8];
#pragma unroll
                for (int s = 0; s < 8; ++s) tmp[s] = (t1 + s < T) ? D2[t1 + s] : 0.f;
                nd2a = float4{tmp[0],tmp[1],tmp[2],tmp[3]};
                nd2b = float4{tmp[4],tmp[5],tmp[6],tmp[7]};
            }
        }

        // (2) out[t] = S_l + S_r for chunk q-1 (S_r now visible in rb)
        if (isL && q >= 1) {
            const int bprev = 4 + ((q - 1) & 1) * hstride;
            const float4 r0 = rb[bprev + 2*lane];
            const float4 r1 = rb[bprev + 2*lane + 1];
            const int tpv = (q - 1) * P + lane * 8;
            if (tpv + 8 <= T) {
                const float4 o0 = {pS0.x + r0.x, pS0.y + r0.y, pS0.z + r0.z, pS0.w + r0.w};
                const float4 o1 = {pS1.x + r1.x, pS1.y + r1.y, pS1.z + r1.z, pS1.w + r1.w};
                *(float4*)(out + tpv)     = o0;
                *(float4*)(out + tpv + 4) = o1;
            } else {
                const float sv[8] = {pS0.x,pS0.y,pS0.z,pS0.w,pS1.x,pS1.y,pS1.z,pS1.w};
                const float rv[8] = {r0.x,r0.y,r0.z,r0.w,r1.x,r1.y,r1.z,r1.w};
#pragma unroll
                for (int s = 0; s < 8; ++s) if (tpv + s < T) out[tpv + s] = sv[s] + rv[s];
            }
        }

        // (3) deferred tail: chunk q-1's last 16 samples -> Pre of half h
        if (act && q >= 1 && lane >= L - 2) {
            const int idx = b4w - 4 + (lane - (L - 2)) * 2;
            buf[idx]     = pS0;
            buf[idx + 1] = pS1;
        }

        // (4) compute chunk q: 8 samples/thread, 13-tap FIR from sliding window
        if (act && q < nphase) {
            const int w0 = b4r + 2 * lane - 3;   // floats [t0-P-12, t0-P+8)
            const float4 W0 = buf[w0],   W1 = buf[w0+1], W2 = buf[w0+2];
            const float4 W3 = buf[w0+3], W4 = buf[w0+4];
            const float win[20] = {W0.x,W0.y,W0.z,W0.w, W1.x,W1.y,W1.z,W1.w,
                                   W2.x,W2.y,W2.z,W2.w, W3.x,W3.y,W3.z,W3.w,
                                   W4.x,W4.y,W4.z,W4.w};
            const float d2v[8] = {d2a.x,d2a.y,d2a.z,d2a.w, d2b.x,d2b.y,d2b.z,d2b.w};
            float S[8];
#pragma unroll
            for (int s = 0; s < 8; ++s) {
                float a0 = 0.f, a1 = 0.f;
#pragma unroll
                for (int k = 0; k < 13; k += 2) a0 += tp.f[k] * win[12 + s - k];
#pragma unroll
                for (int k = 1; k < 13; k += 2) a1 += tp.f[k] * win[12 + s - k];
                S[s] = d2v[s] + tp.g4 * (a0 + a1);
            }
            const float4 S0 = {S[0],S[1],S[2],S[3]}, S1 = {S[4],S[5],S[6],S[7]};
            buf[b4w + 2*lane]     = S0;
            buf[b4w + 2*lane + 1] = S1;
            pS0 = S0; pS1 = S1;
        }
        d2a = nd2a; d2b = nd2b;

        // (5) raw barrier: drain LDS only — global prefetch/stores keep flying
        asm volatile("s_waitcnt lgkmcnt(0)" ::: "memory");
        __builtin_amdgcn_sched_barrier(0);
        __builtin_amdgcn_s_barrier();
        __builtin_amdgcn_sched_barrier(0);
    }
}

extern "C" void kernel_launch(void* const* d_in, const int* in_sizes, int n_in,
                              void* d_out, int out_size, void* d_ws, size_t ws_size,
                              hipStream_t stream) {
    const int*   Lp  = (const int*)  d_in[0];
    const float* pk  = (const float*)d_in[1];
    const float* exc = (const float*)d_in[2];
    const float* gn  = (const float*)d_in[3];
    const float* gb  = (const float*)d_in[4];
    const float* bb  = (const float*)d_in[5];
    const float* da  = (const float*)d_in[6];
    float* out = (float*)d_out;
    float* D2l = (float*)d_ws;
    float* D2r = D2l + out_size;
    const int T = out_size;

    prep_kernel<<<(T + 255) / 256, 256, 0, stream>>>(Lp, pk, exc, gn, gb, bb, da, D2l, D2r, T);
    seq_kernel<<<1, SEQ_BLK, 0, stream>>>(Lp, pk, gn, gb, bb, da, D2l, D2r, out, T);
}

// Round 3
// 80.854 us; speedup vs baseline: 1.4555x; 1.0920x over previous
//
#include <hip/hip_runtime.h>

// Karplus-Strong waveguide, decoupled + lag-doubled (validated round 2):
//   S[t] = D2[t] + g4 * (f ⊛ S)[t-8L],  f = (c⊛d)^{⊛4} (13 taps), g4=(gb*gn)^4
//   D2 = (I + A)(I + A^2) applied to driving terms D, A = g*Z^{2L}*(c⊛d)
//   out = S_l + S_r
// Round 3: seq kernel restructured for conflict-free LDS planes + 16
// samples/thread (4 waves, 1/SIMD); prep stages D_l/D_r in LDS.

#define PREP_BLK 1024
#define SEQ_BLK  256
#define SPAN_MAX 2608   // PREP_BLK + 6*Lmax+9 for L<=256

struct Cfg {
    int L, nUp, nDown, P0, P;
    float gb, gn;
    float c0, c1, c2, d0, d1;
    float w1[4], w2[7], w3[10];  // g*e, g^2*e^{*2}, g^3*e^{*3}
    float f[13];                 // e^{*4}
    float g4;
};

static __device__ __forceinline__ Cfg mkcfg(const int* Lp, const float* pk,
                                            const float* gnp, const float* gbp,
                                            const float* bbp, const float* dap) {
    Cfg cf;
    cf.L = Lp[0];
    const float pluck = pk[0];
    cf.gn = gnp[0]; cf.gb = gbp[0];
    const float bb = bbp[0], da = dap[0];
    cf.nUp = (int)rintf((float)cf.L * pluck);   // round-half-even == jnp.round
    cf.nDown = cf.L - cf.nUp;
    cf.P0 = 2 * cf.L;
    cf.P  = 8 * cf.L;
    cf.c0 = da * (1.f - bb);
    cf.c1 = da * bb + (1.f - da) * (1.f - bb);
    cf.c2 = (1.f - da) * bb;
    cf.d0 = da; cf.d1 = 1.f - da;
    const float e[4] = { cf.c0*cf.d0, cf.c0*cf.d1 + cf.c1*cf.d0,
                         cf.c1*cf.d1 + cf.c2*cf.d0, cf.c2*cf.d1 };
    float ee[7] = {0,0,0,0,0,0,0};
#pragma unroll
    for (int i = 0; i < 4; ++i)
#pragma unroll
        for (int j = 0; j < 4; ++j) ee[i+j] += e[i]*e[j];
    float e3[10] = {0,0,0,0,0,0,0,0,0,0};
#pragma unroll
    for (int i = 0; i < 7; ++i)
#pragma unroll
        for (int j = 0; j < 4; ++j) e3[i+j] += ee[i]*e[j];
    float f4t[13] = {0,0,0,0,0,0,0,0,0,0,0,0,0};
#pragma unroll
    for (int i = 0; i < 7; ++i)
#pragma unroll
        for (int j = 0; j < 7; ++j) f4t[i+j] += ee[i]*ee[j];
    const float g = cf.gb * cf.gn, g2 = g*g, g3 = g2*g;
#pragma unroll
    for (int k = 0; k < 4;  ++k) cf.w1[k] = g  * e[k];
#pragma unroll
    for (int k = 0; k < 7;  ++k) cf.w2[k] = g2 * ee[k];
#pragma unroll
    for (int k = 0; k < 10; ++k) cf.w3[k] = g3 * e3[k];
#pragma unroll
    for (int k = 0; k < 13; ++k) cf.f[k] = f4t[k];
    cf.g4 = g2 * g2;
    return cf;
}

// ---------------- prep: D2_l, D2_r with LDS-staged D arrays ----------------
__global__ __launch_bounds__(PREP_BLK, 1)
void prep_kernel(const int* Lp, const float* pk,
                 const float* __restrict__ exc,
                 const float* gnp, const float* gbp,
                 const float* bbp, const float* dap,
                 float* __restrict__ D2l, float* __restrict__ D2r, int T) {
    __shared__ float Dls[SPAN_MAX];
    __shared__ float Drs[SPAN_MAX];

    const Cfg cf = mkcfg(Lp, pk, gnp, gbp, bbp, dap);
    const int H    = 3 * cf.P0 + 9;          // deepest D-tap back-offset
    const int span = PREP_BLK + H;
    const int t0   = blockIdx.x * PREP_BLK;
    const int base = t0 - H;

    const int mx = (cf.nUp > cf.nDown) ? cf.nUp : cf.nDown;
    const bool safe = (base - cf.L - mx - 2) >= 0;   // no negative exc indices

    // stage 1: D arrays for [base, t0+PREP_BLK)
    for (int j = threadIdx.x; j < span; j += PREP_BLK) {
        const int s = base + j;
        float dl, dr;
        if (safe) {
            dl = 0.5f * exc[s - cf.nDown]
               + (0.5f * cf.gb) * (cf.c0 * exc[s - cf.L     - cf.nUp]
                                 + cf.c1 * exc[s - cf.L - 1 - cf.nUp]
                                 + cf.c2 * exc[s - cf.L - 2 - cf.nUp]);
            dr = 0.5f * exc[s - cf.nUp]
               + (0.5f * cf.gn) * (cf.d0 * exc[s - cf.L     - cf.nDown]
                                 + cf.d1 * exc[s - cf.L - 1 - cf.nDown]);
        } else {
            auto ex = [&](int i) -> float { return (i >= 0) ? exc[i] : 0.f; };
            if (s < 0) { dl = 0.f; dr = 0.f; }
            else {
                dl = 0.5f * ex(s - cf.nDown)
                   + (0.5f * cf.gb) * (cf.c0 * ex(s - cf.L     - cf.nUp)
                                     + cf.c1 * ex(s - cf.L - 1 - cf.nUp)
                                     + cf.c2 * ex(s - cf.L - 2 - cf.nUp));
                dr = 0.5f * ex(s - cf.nUp)
                   + (0.5f * cf.gn) * (cf.d0 * ex(s - cf.L     - cf.nDown)
                                     + cf.d1 * ex(s - cf.L - 1 - cf.nDown));
            }
        }
        Dls[j] = dl; Drs[j] = dr;
    }
    __syncthreads();

    // stage 2: series expansion (stride-1 LDS reads, conflict-free)
    const int t = t0 + threadIdx.x;
    if (t < T) {
        const int p = H + threadIdx.x;
        float al = Dls[p], ar = Drs[p];
#pragma unroll
        for (int k = 0; k < 4;  ++k) { const int j = p -     cf.P0 - k; al += cf.w1[k]*Dls[j]; ar += cf.w1[k]*Drs[j]; }
#pragma unroll
        for (int k = 0; k < 7;  ++k) { const int j = p - 2 * cf.P0 - k; al += cf.w2[k]*Dls[j]; ar += cf.w2[k]*Drs[j]; }
#pragma unroll
        for (int k = 0; k < 10; ++k) { const int j = p - 3 * cf.P0 - k; al += cf.w3[k]*Dls[j]; ar += cf.w3[k]*Drs[j]; }
        D2l[t] = al; D2r[t] = ar;
    }
}

// ---------------- sequential: 50 phases of P=8L samples ----------------
// 256 threads: tid<128 -> S_l (lane=tid), tid>=128 -> S_r (lane=tid-128);
// active lanes 0..NA-1, NA = P/16 (=120). Each thread owns 16 consecutive
// samples/chunk in registers. Prev chunk lives in LDS planes pl[par][arr][m][lane]
// (lane-stride 1 float4 -> full-bank). Window for chunk q = 12 floats from
// lane-1's planes 1..3 + own 16 regs. Lane 0 reads chunk q-2's tail from a
// 3-slot 'pre' ring (slot q%3 written, (q-2)%3 read -> never same-phase).
static __device__ __forceinline__ float4 f4add(float4 a, float4 b) {
    return float4{a.x+b.x, a.y+b.y, a.z+b.z, a.w+b.w};
}

__global__ __launch_bounds__(SEQ_BLK, 1)
void seq_kernel(const int* Lp, const float* pk,
                const float* gnp, const float* gbp, const float* bbp, const float* dap,
                const float* __restrict__ D2l, const float* __restrict__ D2r,
                float* __restrict__ out, int T) {
    __shared__ float4 pl[2][2][4][128];   // [parity][arr][plane m][lane]
    __shared__ float4 pre[3][2][3];       // [q%3][arr][slot]

    const Cfg cf = mkcfg(Lp, pk, gnp, gbp, bbp, dap);
    const int P  = cf.P;
    const int NA = P >> 4;                // threads per array (120 for L=240)
    const int tid = threadIdx.x;
    const int arr = tid >> 7;
    const int lam = tid & 127;
    const bool act = lam < NA;
    const float* __restrict__ D2 = arr ? D2r : D2l;

    {   // zero planes + pre (chunk -1 / -2 are silence)
        float4* p0 = &pl[0][0][0][0];
        for (int i = tid; i < 2*2*4*128; i += SEQ_BLK) p0[i] = float4{0,0,0,0};
        if (tid < 18) (&pre[0][0][0])[tid] = float4{0,0,0,0};
    }
    __syncthreads();

    const int nphase = (T + P - 1) / P;   // 50 (exact for T=96000, L=240)

    float4 pS0{0,0,0,0}, pS1{0,0,0,0}, pS2{0,0,0,0}, pS3{0,0,0,0};

    auto load16 = [&](int t, float4& a, float4& b, float4& c, float4& d) {
        if (t + 16 <= T) {
            a = *(const float4*)(D2 + t);      b = *(const float4*)(D2 + t + 4);
            c = *(const float4*)(D2 + t + 8);  d = *(const float4*)(D2 + t + 12);
        } else {
            float tmp[16];
#pragma unroll
            for (int s = 0; s < 16; ++s) tmp[s] = (t + s < T) ? D2[t + s] : 0.f;
            a = float4{tmp[0],tmp[1],tmp[2],tmp[3]};   b = float4{tmp[4],tmp[5],tmp[6],tmp[7]};
            c = float4{tmp[8],tmp[9],tmp[10],tmp[11]}; d = float4{tmp[12],tmp[13],tmp[14],tmp[15]};
        }
    };

    float4 dA{0,0,0,0}, dB{0,0,0,0}, dC{0,0,0,0}, dD{0,0,0,0};
    if (act) load16(lam << 4, dA, dB, dC, dD);

    for (int q = 0; q <= nphase; ++q) {
        const int par = q & 1;

        // (1) prefetch next chunk's D2 (stays in flight across the raw barrier)
        float4 nA{0,0,0,0}, nB{0,0,0,0}, nC{0,0,0,0}, nD{0,0,0,0};
        if (act && (q + 1) < nphase) load16((q + 1) * P + (lam << 4), nA, nB, nC, nD);

        // (2) out for chunk q-1: own pS (S_l) + R's planes (S_r)
        if (arr == 0 && act && q >= 1) {
            const int pp = par ^ 1;
            const float4 r0 = pl[pp][1][0][lam], r1 = pl[pp][1][1][lam];
            const float4 r2 = pl[pp][1][2][lam], r3 = pl[pp][1][3][lam];
            const int tpv = (q - 1) * P + (lam << 4);
            if (tpv + 16 <= T) {
                *(float4*)(out + tpv)      = f4add(pS0, r0);
                *(float4*)(out + tpv + 4)  = f4add(pS1, r1);
                *(float4*)(out + tpv + 8)  = f4add(pS2, r2);
                *(float4*)(out + tpv + 12) = f4add(pS3, r3);
            } else {
                const float sv[16] = {pS0.x,pS0.y,pS0.z,pS0.w, pS1.x,pS1.y,pS1.z,pS1.w,
                                      pS2.x,pS2.y,pS2.z,pS2.w, pS3.x,pS3.y,pS3.z,pS3.w};
                const float rv[16] = {r0.x,r0.y,r0.z,r0.w, r1.x,r1.y,r1.z,r1.w,
                                      r2.x,r2.y,r2.z,r2.w, r3.x,r3.y,r3.z,r3.w};
#pragma unroll
                for (int s = 0; s < 16; ++s) if (tpv + s < T) out[tpv + s] = sv[s] + rv[s];
            }
        }

        // (3)+(4) compute chunk q
        if (act && q < nphase) {
            float4 W0, W1, W2;
            if (lam == 0) {
                const int rs = (q + 1) % 3;    // slot written at phase q-2
                W0 = pre[rs][arr][0]; W1 = pre[rs][arr][1]; W2 = pre[rs][arr][2];
            } else {
                W0 = pl[par ^ 1][arr][1][lam - 1];
                W1 = pl[par ^ 1][arr][2][lam - 1];
                W2 = pl[par ^ 1][arr][3][lam - 1];
            }
            const float win[28] = {W0.x,W0.y,W0.z,W0.w, W1.x,W1.y,W1.z,W1.w,
                                   W2.x,W2.y,W2.z,W2.w,
                                   pS0.x,pS0.y,pS0.z,pS0.w, pS1.x,pS1.y,pS1.z,pS1.w,
                                   pS2.x,pS2.y,pS2.z,pS2.w, pS3.x,pS3.y,pS3.z,pS3.w};
            const float dv[16] = {dA.x,dA.y,dA.z,dA.w, dB.x,dB.y,dB.z,dB.w,
                                  dC.x,dC.y,dC.z,dC.w, dD.x,dD.y,dD.z,dD.w};
            float S[16];
#pragma unroll
            for (int s = 0; s < 16; ++s) {
                float a0 = 0.f, a1 = 0.f;
#pragma unroll
                for (int k = 0; k < 13; k += 2) a0 += cf.f[k] * win[12 + s - k];
#pragma unroll
                for (int k = 1; k < 13; k += 2) a1 += cf.f[k] * win[12 + s - k];
                S[s] = dv[s] + cf.g4 * (a0 + a1);
            }
            pS0 = float4{S[0],S[1],S[2],S[3]};   pS1 = float4{S[4],S[5],S[6],S[7]};
            pS2 = float4{S[8],S[9],S[10],S[11]}; pS3 = float4{S[12],S[13],S[14],S[15]};

            pl[par][arr][0][lam] = pS0;
            pl[par][arr][1][lam] = pS1;
            pl[par][arr][2][lam] = pS2;
            pl[par][arr][3][lam] = pS3;
            if (lam == NA - 1) {   // chunk tail -> pre ring for lane 0 at q+2
                pre[q % 3][arr][0] = pS1;
                pre[q % 3][arr][1] = pS2;
                pre[q % 3][arr][2] = pS3;
            }
        }
        dA = nA; dB = nB; dC = nC; dD = nD;

        // (5) raw barrier: drain LDS only — global loads/stores keep flying
        asm volatile("s_waitcnt lgkmcnt(0)" ::: "memory");
        __builtin_amdgcn_sched_barrier(0);
        __builtin_amdgcn_s_barrier();
        __builtin_amdgcn_sched_barrier(0);
    }
}

extern "C" void kernel_launch(void* const* d_in, const int* in_sizes, int n_in,
                              void* d_out, int out_size, void* d_ws, size_t ws_size,
                              hipStream_t stream) {
    const int*   Lp  = (const int*)  d_in[0];
    const float* pk  = (const float*)d_in[1];
    const float* exc = (const float*)d_in[2];
    const float* gn  = (const float*)d_in[3];
    const float* gb  = (const float*)d_in[4];
    const float* bb  = (const float*)d_in[5];
    const float* da  = (const float*)d_in[6];
    float* out = (float*)d_out;
    float* D2l = (float*)d_ws;
    float* D2r = D2l + out_size;
    const int T = out_size;

    prep_kernel<<<(T + PREP_BLK - 1) / PREP_BLK, PREP_BLK, 0, stream>>>(
        Lp, pk, exc, gn, gb, bb, da, D2l, D2r, T);
    seq_kernel<<<1, SEQ_BLK, 0, stream>>>(Lp, pk, gn, gb, bb, da, D2l, D2r, out, T);
}